// Round 4
// baseline (898.978 us; speedup 1.0000x reference)
//
#include <hip/hip_runtime.h>

#define NN 100000
#define EC 6400000
#define ED 400000
#define BN_EPS 1e-5f
#define NSB ((NN + 255) >> 8)    // 391 buckets of 256 nodes
#define SCAP 32                  // staging ring slots per bucket (2 x 16-groups)
#define CSR_CAP 19200            // LDS CSR build capacity (mean 16384 + 22 sigma)

// ---------------- preprocessing v3: append-stream bucket sort ----------------
// R3's scatter had 5.8x write amplification (148MB for 25.6MB payload): 400K
// tiny pre-reserved regions open simultaneously thrashed L2. Now each bucket
// is a sequential append stream (global cursor): active write footprint = 391
// tail lines (~25KB). LDS stages 16-entry groups -> 64B flushes, 400K atomics
// total instead of 6.4M.

__global__ __launch_bounds__(256)
void sb_hist(const int* __restrict__ ei, int E, int* __restrict__ gtot) {
    __shared__ int h[NSB];
    for (int i = threadIdx.x; i < NSB; i += 256) h[i] = 0;
    __syncthreads();
    int t = blockIdx.x * 256 + threadIdx.x, stride = gridDim.x * 256;
    for (int e = t; e < E; e += stride) atomicAdd(&h[ei[E + e] >> 8], 1);
    __syncthreads();
    for (int i = threadIdx.x; i < NSB; i += 256) if (h[i]) atomicAdd(&gtot[i], h[i]);
}

// one block: padded exclusive scan (16-aligned bases) for both graphs; init cursors
__global__ void sb_base(const int* __restrict__ gtot_c, int* __restrict__ bbase_c, int* __restrict__ gcur_c,
                        const int* __restrict__ gtot_d, int* __restrict__ bbase_d, int* __restrict__ gcur_d) {
    __shared__ int wsum[4];
    __shared__ int carry;
    int lane = threadIdx.x & 63, w = threadIdx.x >> 6;
    for (int which = 0; which < 2; ++which) {
        const int* gt = which ? gtot_d : gtot_c;
        int* bb = which ? bbase_d : bbase_c;
        int* gc = which ? gcur_d : gcur_c;
        if (threadIdx.x == 0) carry = 0;
        __syncthreads();
        for (int s = 0; s < NSB; s += 256) {
            int idx = s + threadIdx.x;
            int v = (idx < NSB) ? ((gt[idx] + 15) & ~15) : 0;   // padded size
            int x = v;
            #pragma unroll
            for (int sh = 1; sh < 64; sh <<= 1) { int y = __shfl_up(x, sh); if (lane >= sh) x += y; }
            if (lane == 63) wsum[w] = x;
            __syncthreads();
            int wb = 0;
            #pragma unroll
            for (int j = 0; j < 4; ++j) if (j < w) wb += wsum[j];
            int all = wsum[0] + wsum[1] + wsum[2] + wsum[3];
            if (idx < NSB) { int base = carry + wb + x - v; bb[idx] = base; gc[idx] = base; }
            __syncthreads();
            if (threadIdx.x == 0) carry += all;
            __syncthreads();
        }
    }
}

// LDS-staged scatter: deposit -> sync -> designated-thread 64B flushes
__global__ __launch_bounds__(256)
void sb_scatter(const int* __restrict__ ei, int E,
                int* __restrict__ gcur, unsigned* __restrict__ packed) {
    __shared__ __align__(16) unsigned stage[NSB][SCAP];
    __shared__ int cnt[NSB];
    __shared__ int flushed[NSB];
    for (int i = threadIdx.x; i < NSB; i += 256) { cnt[i] = 0; flushed[i] = 0; }
    __syncthreads();
    int stride = gridDim.x * 256;
    for (int e0 = blockIdx.x * 256; e0 < E; e0 += stride) {
        int idx = e0 + threadIdx.x;
        if (idx < E) {
            int src = ei[idx], dst = ei[E + idx];
            int b = dst >> 8;
            unsigned v = (unsigned)src | ((unsigned)(dst & 255) << 17);
            int pos = atomicAdd(&cnt[b], 1);
            if (pos - flushed[b] < SCAP) {          // flushed stable during deposit
                stage[b][pos & (SCAP - 1)] = v;
            } else {                                 // ~never: direct append
                int gp = atomicAdd(&gcur[b], 1);
                packed[gp] = v;
            }
        }
        __syncthreads();
        for (int b = threadIdx.x; b < NSB; b += 256) {
            int c = cnt[b], f = flushed[b];
            while (c - f >= 16) {
                int gp = atomicAdd(&gcur[b], 16);
                int s0 = f & (SCAP - 1);            // 0 or 16
                if ((gp & 3) == 0) {
                    const uint4* s4 = (const uint4*)&stage[b][s0];
                    uint4* d4 = (uint4*)&packed[gp];
                    d4[0] = s4[0]; d4[1] = s4[1]; d4[2] = s4[2]; d4[3] = s4[3];
                } else {
                    for (int j = 0; j < 16; ++j) packed[gp + j] = stage[b][s0 + j];
                }
                f += 16;
            }
            flushed[b] = f;
        }
        __syncthreads();
    }
    // tail: <16 leftovers per bucket, compact sequential positions
    for (int b = threadIdx.x; b < NSB; b += 256) {
        int c = cnt[b], f = flushed[b], k = c - f;
        if (k > 0) {
            int gp = atomicAdd(&gcur[b], k);
            for (int j = 0; j < k; ++j) packed[gp + j] = stage[b][(f + j) & (SCAP - 1)];
        }
    }
}

// one block per 256-node bucket: exact CSR built in LDS, written coalesced
__global__ __launch_bounds__(256)
void sb_csr(const unsigned* __restrict__ packed,
            const int* __restrict__ bbase, const int* __restrict__ gtot,
            int* __restrict__ csr, int* __restrict__ offs, int* __restrict__ deg,
            float* __restrict__ inv) {
    __shared__ int h[256];
    __shared__ int loff[256];
    __shared__ int ws2[4];
    __shared__ int ebuf[CSR_CAP];
    int b = blockIdx.x;
    int ebeg = bbase[b], ecnt = gtot[b];
    int node0 = b << 8;
    int nn = min(256, NN - node0);
    h[threadIdx.x] = 0;
    __syncthreads();
    for (int e = threadIdx.x; e < ecnt; e += 256)
        atomicAdd(&h[packed[ebeg + e] >> 17], 1);
    __syncthreads();
    {
        int lane = threadIdx.x & 63, w = threadIdx.x >> 6;
        int v = h[threadIdx.x], x = v;
        #pragma unroll
        for (int sh = 1; sh < 64; sh <<= 1) { int y = __shfl_up(x, sh); if (lane >= sh) x += y; }
        if (lane == 63) ws2[w] = x;
        __syncthreads();
        int wb = 0;
        #pragma unroll
        for (int j = 0; j < 4; ++j) if (j < w) wb += ws2[j];
        int excl = wb + x - v;
        loff[threadIdx.x] = excl;
        if (threadIdx.x < nn) {
            int node = node0 + threadIdx.x;
            offs[node] = ebeg + excl;
            deg[node]  = v;
            inv[node]  = 1.0f / (float)(v > 1 ? v : 1);
        }
    }
    __syncthreads();
    if (ecnt <= CSR_CAP) {
        for (int e = threadIdx.x; e < ecnt; e += 256) {
            unsigned u = packed[ebeg + e];
            int p = atomicAdd(&loff[u >> 17], 1);
            ebuf[p] = (int)(u & 0x1FFFF);
        }
        __syncthreads();
        for (int e = threadIdx.x; e < ecnt; e += 256) csr[ebeg + e] = ebuf[e];
    } else {   // overflow fallback (never fires for this data)
        for (int e = threadIdx.x; e < ecnt; e += 256) {
            unsigned u = packed[ebeg + e];
            int p = atomicAdd(&loff[u >> 17], 1);
            csr[ebeg + p] = (int)(u & 0x1FFFF);
        }
    }
}

// ---------------- fused SAGE layer (unchanged from R3) ----------------
template<int FIN_, bool APPLY_BN>
__global__ __launch_bounds__(256)
void sage_layer(const float* __restrict__ hin,
                const float* __restrict__ stats_in,   // padded: [f*16]=sum, [(8+f)*16]=sumsq
                const float* __restrict__ gin, const float* __restrict__ bin,
                const int* __restrict__ offs, const int* __restrict__ deg,
                const int* __restrict__ csr, const float* __restrict__ inv,
                const float* __restrict__ Wl, const float* __restrict__ Wr,
                float* __restrict__ hout,
                float* __restrict__ stats_out) {
    __shared__ float bl[16];
    int tid = threadIdx.x;
    if (tid < 16) bl[tid] = 0.f;
    __syncthreads();

    int wave = tid >> 6;
    int lane = tid & 63;
    int e8 = lane >> 3;
    int f  = lane & 7;

    float sc = 1.f, sh = 0.f;
    if constexpr (APPLY_BN) {
        float m = stats_in[f * 16] * (1.0f / NN);
        float v = stats_in[(8 + f) * 16] * (1.0f / NN) - m * m;
        float is = rsqrtf(v + BN_EPS);
        sc = gin[f] * is;
        sh = bin[f] - m * sc;
    }

    const bool actf = (f < FIN_);
    const int W = gridDim.x * 4;
    float acc_r = 0.f, acc_r2 = 0.f;

    for (int i = blockIdx.x * 4 + wave; i < NN; i += W) {
        int d = deg[i];
        int o = offs[i];
        float s = 0.f;
        for (int base = 0; base < d; base += 64) {
            int rem = d - base;
            int c = 0;
            if (lane < rem) c = csr[o + base + lane];
            #pragma unroll
            for (int it = 0; it < 8; ++it) {
                int j = it * 8 + e8;
                int src = __shfl(c, j);
                if ((base + j) < d && actf) {
                    float v = hin[src * FIN_ + f];
                    if constexpr (APPLY_BN) v = fmaf(v, sc, sh);
                    s += v;
                }
            }
        }
        s += __shfl_xor(s, 8);
        s += __shfl_xor(s, 16);
        s += __shfl_xor(s, 32);
        float meanf = s * inv[i];

        float hf = 0.f;
        if (actf) {
            hf = hin[i * FIN_ + f];
            if constexpr (APPLY_BN) hf = fmaf(hf, sc, sh);
        }

        float y = 0.f;
        int gbase = lane & ~7;
        #pragma unroll
        for (int k = 0; k < FIN_; ++k) {
            float mk = __shfl(meanf, gbase + k);
            float hk = __shfl(hf, gbase + k);
            y = fmaf(mk, Wl[f * FIN_ + k], y);
            y = fmaf(hk, Wr[f * FIN_ + k], y);
        }
        float n2 = y * y;
        n2 += __shfl_xor(n2, 1);
        n2 += __shfl_xor(n2, 2);
        n2 += __shfl_xor(n2, 4);
        float z = y / fmaxf(sqrtf(n2), 1e-12f);
        float r = fmaxf(z, 0.f);
        if (e8 == 0) hout[i * 8 + f] = r;
        acc_r  += r;
        acc_r2 += r * r;
    }

    if (e8 == 0) {
        atomicAdd(&bl[f], acc_r);
        atomicAdd(&bl[8 + f], acc_r2);
    }
    __syncthreads();
    if (tid < 16) atomicAdd(&stats_out[tid * 16], bl[tid]);   // 1 cache line per feature
}

__global__ void apply_bn_out(const float* __restrict__ hin,
                             const float* __restrict__ stats,
                             const float* __restrict__ g, const float* __restrict__ b,
                             float* __restrict__ out) {
    int t = blockIdx.x * blockDim.x + threadIdx.x;
    if (t >= NN * 8) return;
    int f = t & 7;
    float m = stats[f * 16] * (1.0f / NN);
    float v = stats[(8 + f) * 16] * (1.0f / NN) - m * m;
    float sc = g[f] * rsqrtf(v + BN_EPS);
    float sh = b[f] - m * sc;
    out[t] = fmaf(hin[t], sc, sh);
}

// ---------------- launch ----------------

static inline char* bump(char*& p, size_t bytes) {
    char* r = p;
    p += (bytes + 255) & ~(size_t)255;
    return r;
}

extern "C" void kernel_launch(void* const* d_in, const int* in_sizes, int n_in,
                              void* d_out, int out_size, void* d_ws, size_t ws_size,
                              hipStream_t stream) {
    const float* x   = (const float*)d_in[0];
    const int* eic   = (const int*)d_in[1];
    const int* eid   = (const int*)d_in[2];
    const float* W1l = (const float*)d_in[3];
    const float* W1r = (const float*)d_in[4];
    const float* W2l = (const float*)d_in[5];
    const float* W2r = (const float*)d_in[6];
    const float* W3l = (const float*)d_in[7];
    const float* W3r = (const float*)d_in[8];
    const float* W4l = (const float*)d_in[9];
    const float* W4r = (const float*)d_in[10];
    const float* g1 = (const float*)d_in[11];
    const float* b1 = (const float*)d_in[12];
    const float* g2 = (const float*)d_in[13];
    const float* b2 = (const float*)d_in[14];
    const float* g3 = (const float*)d_in[15];
    const float* b3 = (const float*)d_in[16];
    const float* g4 = (const float*)d_in[17];
    const float* b4 = (const float*)d_in[18];
    float* out = (float*)d_out;

    const size_t PAD = 16 * NSB;   // per-bucket 16-alignment padding

    char* p = (char*)d_ws;
    float* stats  = (float*)bump(p, 5 * 256 * 4);   // zero region start
    int*   gtot_c = (int*)  bump(p, NSB * 4);
    int*   gtot_d = (int*)  bump(p, NSB * 4);
    size_t zero_bytes = (size_t)(p - (char*)d_ws);
    int*   bbase_c = (int*)  bump(p, NSB * 4);
    int*   gcur_c  = (int*)  bump(p, NSB * 4);
    int*   bbase_d = (int*)  bump(p, NSB * 4);
    int*   gcur_d  = (int*)  bump(p, NSB * 4);
    int*   offs_c  = (int*)  bump(p, NN * 4);
    int*   deg_c   = (int*)  bump(p, NN * 4);
    float* inv_c   = (float*)bump(p, NN * 4);
    int*   offs_d  = (int*)  bump(p, NN * 4);
    int*   deg_d   = (int*)  bump(p, NN * 4);
    float* inv_d   = (float*)bump(p, NN * 4);
    int*   csr_c   = (int*)  bump(p, (EC + PAD) * 4);
    int*   csr_d   = (int*)  bump(p, (ED + PAD) * 4);
    unsigned* packed_d = (unsigned*)bump(p, (ED + PAD) * 4);
    // packed_c dead after sb_csr; overlay activation ping-pong buffers on it
    char* pc = p;
    unsigned* packed_c = (unsigned*)bump(p, (EC + PAD) * 4);
    char* pr = pc;
    float* r_a = (float*)bump(pr, NN * 8 * 4);
    float* r_b = (float*)bump(pr, NN * 8 * 4);
    (void)ws_size; (void)in_sizes; (void)n_in; (void)out_size;

    hipMemsetAsync(d_ws, 0, zero_bytes, stream);

    sb_hist<<<512, 256, 0, stream>>>(eic, EC, gtot_c);
    sb_hist<<<128, 256, 0, stream>>>(eid, ED, gtot_d);
    sb_base<<<1, 256, 0, stream>>>(gtot_c, bbase_c, gcur_c, gtot_d, bbase_d, gcur_d);
    sb_scatter<<<512, 256, 0, stream>>>(eic, EC, gcur_c, packed_c);
    sb_scatter<<<128, 256, 0, stream>>>(eid, ED, gcur_d, packed_d);
    sb_csr<<<NSB, 256, 0, stream>>>(packed_c, bbase_c, gtot_c, csr_c, offs_c, deg_c, inv_c);
    sb_csr<<<NSB, 256, 0, stream>>>(packed_d, bbase_d, gtot_d, csr_d, offs_d, deg_d, inv_d);

    const int LB = 2048;   // 8192 waves; grid-stride over nodes
    sage_layer<5, false><<<LB, 256, 0, stream>>>(
        x, nullptr, nullptr, nullptr,
        offs_c, deg_c, csr_c, inv_c, W1l, W1r, r_a, stats + 0);
    sage_layer<8, true><<<LB, 256, 0, stream>>>(
        r_a, stats + 0, g1, b1,
        offs_c, deg_c, csr_c, inv_c, W4l, W4r, r_b, stats + 256);
    sage_layer<8, true><<<LB, 256, 0, stream>>>(
        r_b, stats + 256, g2, b2,
        offs_d, deg_d, csr_d, inv_d, W2l, W2r, r_a, stats + 512);
    sage_layer<8, true><<<LB, 256, 0, stream>>>(
        r_a, stats + 512, g3, b3,
        offs_c, deg_c, csr_c, inv_c, W3l, W3r, r_b, stats + 768);
    sage_layer<8, true><<<LB, 256, 0, stream>>>(
        r_b, stats + 768, g4, b4,
        offs_c, deg_c, csr_c, inv_c, W3l, W3r, r_a, stats + 1024);
    apply_bn_out<<<(NN * 8 + 255) / 256, 256, 0, stream>>>(r_a, stats + 1024, g4, b4, out);
}

// Round 5
// 730.262 us; speedup vs baseline: 1.2310x; 1.2310x over previous
//
#include <hip/hip_runtime.h>

#define NN 100000
#define EC 6400000
#define ED 400000
#define BN_EPS 1e-5f
#define NSB ((NN + 255) >> 8)    // 391 buckets of 256 nodes
#define NCH 256                  // edge chunks == scatter/hist grid
#define CSR_CAP 19200            // LDS CSR build capacity (mean 16384 + 22 sigma)
#define CHUNK_OF(E) (((((E) + NCH - 1) / NCH) + 3) & ~3)   // 4-aligned chunk

// ---------------- preprocessing v4: big-region reserved scatter ----------------
// R3 (pre-reserved regions, 16 edges each): simple but 5.8x write amp.
// R4 (append streams + LDS staging): 1.5x amp but 3.45M LDS bank conflicts
// (stage row stride 32 = single-bank flush reads) + protocol serialization.
// v4 = R3 structure with 64-edge (4-line) regions and 1024-thread blocks:
// no staging, no protocol, amp ~1.3x, 50% occupancy.

__global__ __launch_bounds__(1024)
void hist_pass(const int* __restrict__ ei, int E, int* __restrict__ bhist) {
    __shared__ int h[NSB];
    for (int i = threadIdx.x; i < NSB; i += 1024) h[i] = 0;
    __syncthreads();
    int k = blockIdx.x;
    int chunk = CHUNK_OF(E);
    int beg = k * chunk, end = min(E, beg + chunk);
    for (int e = beg + threadIdx.x * 4; e < end; e += 1024 * 4) {
        int4 d4 = *(const int4*)&ei[E + e];   // E%4==0, beg%4==0 -> aligned
        atomicAdd(&h[d4.x >> 8], 1);
        atomicAdd(&h[d4.y >> 8], 1);
        atomicAdd(&h[d4.z >> 8], 1);
        atomicAdd(&h[d4.w >> 8], 1);
    }
    __syncthreads();
    for (int i = threadIdx.x; i < NSB; i += 1024) bhist[i * NCH + k] = h[i];
}

// per-bucket exclusive scan over its NCH chunk counts (in place) + total
__global__ __launch_bounds__(256)
void row_scan(int* __restrict__ bhist, int* __restrict__ total) {
    int b = blockIdx.x;
    int* row = bhist + b * NCH;
    __shared__ int wsum[4];
    int lane = threadIdx.x & 63, w = threadIdx.x >> 6;
    int v = row[threadIdx.x];                 // NCH == blockDim == 256
    int x = v;
    #pragma unroll
    for (int sh = 1; sh < 64; sh <<= 1) { int y = __shfl_up(x, sh); if (lane >= sh) x += y; }
    if (lane == 63) wsum[w] = x;
    __syncthreads();
    int wb = 0;
    #pragma unroll
    for (int j = 0; j < 4; ++j) if (j < w) wb += wsum[j];
    row[threadIdx.x] = wb + x - v;            // exclusive
    if (threadIdx.x == 255) total[b] = wb + x;
}

// exclusive scan over NSB bucket totals -> bucket edge bases
__global__ void bucket_base(const int* __restrict__ total, int* __restrict__ bbase) {
    __shared__ int wsum[4];
    __shared__ int carry;
    if (threadIdx.x == 0) carry = 0;
    __syncthreads();
    int lane = threadIdx.x & 63, w = threadIdx.x >> 6;
    for (int s = 0; s < NSB; s += 256) {
        int idx = s + threadIdx.x;
        int v = (idx < NSB) ? total[idx] : 0;
        int x = v;
        #pragma unroll
        for (int sh = 1; sh < 64; sh <<= 1) { int y = __shfl_up(x, sh); if (lane >= sh) x += y; }
        if (lane == 63) wsum[w] = x;
        __syncthreads();
        int wb = 0;
        #pragma unroll
        for (int j = 0; j < 4; ++j) if (j < w) wb += wsum[j];
        int all = wsum[0] + wsum[1] + wsum[2] + wsum[3];
        if (idx < NSB) bbase[idx] = carry + wb + x - v;
        __syncthreads();
        if (threadIdx.x == 0) carry += all;
        __syncthreads();
    }
}

// scatter into per-(chunk,bucket) reserved regions; packed (src:17 | ldst<<17)
__global__ __launch_bounds__(1024)
void scatter_pairs(const int* __restrict__ ei, int E,
                   const int* __restrict__ bhist, const int* __restrict__ bbase,
                   unsigned* __restrict__ packed) {
    __shared__ int cur[NSB];
    int k = blockIdx.x;
    for (int b = threadIdx.x; b < NSB; b += 1024)
        cur[b] = bbase[b] + bhist[b * NCH + k];
    __syncthreads();
    int chunk = CHUNK_OF(E);
    int beg = k * chunk, end = min(E, beg + chunk);
    for (int e = beg + threadIdx.x * 4; e < end; e += 1024 * 4) {
        int4 s4 = *(const int4*)&ei[e];
        int4 d4 = *(const int4*)&ei[E + e];
        {
            int p = atomicAdd(&cur[d4.x >> 8], 1);
            packed[p] = (unsigned)s4.x | ((unsigned)(d4.x & 255) << 17);
        }
        {
            int p = atomicAdd(&cur[d4.y >> 8], 1);
            packed[p] = (unsigned)s4.y | ((unsigned)(d4.y & 255) << 17);
        }
        {
            int p = atomicAdd(&cur[d4.z >> 8], 1);
            packed[p] = (unsigned)s4.z | ((unsigned)(d4.z & 255) << 17);
        }
        {
            int p = atomicAdd(&cur[d4.w >> 8], 1);
            packed[p] = (unsigned)s4.w | ((unsigned)(d4.w & 255) << 17);
        }
    }
}

// one block per 256-node bucket: exact CSR built in LDS, written coalesced
__global__ __launch_bounds__(256)
void sb_csr(const unsigned* __restrict__ packed,
            const int* __restrict__ bbase, const int* __restrict__ total,
            int* __restrict__ csr, int* __restrict__ offs, int* __restrict__ deg,
            float* __restrict__ inv) {
    __shared__ int h[256];
    __shared__ int loff[256];
    __shared__ int ws2[4];
    __shared__ int ebuf[CSR_CAP];
    int b = blockIdx.x;
    int ebeg = bbase[b], ecnt = total[b];
    int node0 = b << 8;
    int nn = min(256, NN - node0);
    h[threadIdx.x] = 0;
    __syncthreads();
    for (int e = threadIdx.x; e < ecnt; e += 256)
        atomicAdd(&h[packed[ebeg + e] >> 17], 1);
    __syncthreads();
    {
        int lane = threadIdx.x & 63, w = threadIdx.x >> 6;
        int v = h[threadIdx.x], x = v;
        #pragma unroll
        for (int sh = 1; sh < 64; sh <<= 1) { int y = __shfl_up(x, sh); if (lane >= sh) x += y; }
        if (lane == 63) ws2[w] = x;
        __syncthreads();
        int wb = 0;
        #pragma unroll
        for (int j = 0; j < 4; ++j) if (j < w) wb += ws2[j];
        int excl = wb + x - v;
        loff[threadIdx.x] = excl;
        if (threadIdx.x < nn) {
            int node = node0 + threadIdx.x;
            offs[node] = ebeg + excl;
            deg[node]  = v;
            inv[node]  = 1.0f / (float)(v > 1 ? v : 1);
        }
    }
    __syncthreads();
    if (ecnt <= CSR_CAP) {
        for (int e = threadIdx.x; e < ecnt; e += 256) {
            unsigned u = packed[ebeg + e];
            int p = atomicAdd(&loff[u >> 17], 1);
            ebuf[p] = (int)(u & 0x1FFFF);
        }
        __syncthreads();
        for (int e = threadIdx.x; e < ecnt; e += 256) csr[ebeg + e] = ebuf[e];
    } else {   // overflow fallback (never fires for Poisson(64) buckets)
        for (int e = threadIdx.x; e < ecnt; e += 256) {
            unsigned u = packed[ebeg + e];
            int p = atomicAdd(&loff[u >> 17], 1);
            csr[ebeg + p] = (int)(u & 0x1FFFF);
        }
    }
}

// ---------------- fused SAGE layer (unchanged from R3/R4) ----------------
template<int FIN_, bool APPLY_BN>
__global__ __launch_bounds__(256)
void sage_layer(const float* __restrict__ hin,
                const float* __restrict__ stats_in,   // padded: [f*16]=sum, [(8+f)*16]=sumsq
                const float* __restrict__ gin, const float* __restrict__ bin,
                const int* __restrict__ offs, const int* __restrict__ deg,
                const int* __restrict__ csr, const float* __restrict__ inv,
                const float* __restrict__ Wl, const float* __restrict__ Wr,
                float* __restrict__ hout,
                float* __restrict__ stats_out) {
    __shared__ float bl[16];
    int tid = threadIdx.x;
    if (tid < 16) bl[tid] = 0.f;
    __syncthreads();

    int wave = tid >> 6;
    int lane = tid & 63;
    int e8 = lane >> 3;
    int f  = lane & 7;

    float sc = 1.f, sh = 0.f;
    if constexpr (APPLY_BN) {
        float m = stats_in[f * 16] * (1.0f / NN);
        float v = stats_in[(8 + f) * 16] * (1.0f / NN) - m * m;
        float is = rsqrtf(v + BN_EPS);
        sc = gin[f] * is;
        sh = bin[f] - m * sc;
    }

    const bool actf = (f < FIN_);
    const int W = gridDim.x * 4;
    float acc_r = 0.f, acc_r2 = 0.f;

    for (int i = blockIdx.x * 4 + wave; i < NN; i += W) {
        int d = deg[i];
        int o = offs[i];
        float s = 0.f;
        for (int base = 0; base < d; base += 64) {
            int rem = d - base;
            int c = 0;
            if (lane < rem) c = csr[o + base + lane];
            #pragma unroll
            for (int it = 0; it < 8; ++it) {
                int j = it * 8 + e8;
                int src = __shfl(c, j);
                if ((base + j) < d && actf) {
                    float v = hin[src * FIN_ + f];
                    if constexpr (APPLY_BN) v = fmaf(v, sc, sh);
                    s += v;
                }
            }
        }
        s += __shfl_xor(s, 8);
        s += __shfl_xor(s, 16);
        s += __shfl_xor(s, 32);
        float meanf = s * inv[i];

        float hf = 0.f;
        if (actf) {
            hf = hin[i * FIN_ + f];
            if constexpr (APPLY_BN) hf = fmaf(hf, sc, sh);
        }

        float y = 0.f;
        int gbase = lane & ~7;
        #pragma unroll
        for (int k = 0; k < FIN_; ++k) {
            float mk = __shfl(meanf, gbase + k);
            float hk = __shfl(hf, gbase + k);
            y = fmaf(mk, Wl[f * FIN_ + k], y);
            y = fmaf(hk, Wr[f * FIN_ + k], y);
        }
        float n2 = y * y;
        n2 += __shfl_xor(n2, 1);
        n2 += __shfl_xor(n2, 2);
        n2 += __shfl_xor(n2, 4);
        float z = y / fmaxf(sqrtf(n2), 1e-12f);
        float r = fmaxf(z, 0.f);
        if (e8 == 0) hout[i * 8 + f] = r;
        acc_r  += r;
        acc_r2 += r * r;
    }

    if (e8 == 0) {
        atomicAdd(&bl[f], acc_r);
        atomicAdd(&bl[8 + f], acc_r2);
    }
    __syncthreads();
    if (tid < 16) atomicAdd(&stats_out[tid * 16], bl[tid]);   // 1 cache line per feature
}

__global__ void apply_bn_out(const float* __restrict__ hin,
                             const float* __restrict__ stats,
                             const float* __restrict__ g, const float* __restrict__ b,
                             float* __restrict__ out) {
    int t = blockIdx.x * blockDim.x + threadIdx.x;
    if (t >= NN * 8) return;
    int f = t & 7;
    float m = stats[f * 16] * (1.0f / NN);
    float v = stats[(8 + f) * 16] * (1.0f / NN) - m * m;
    float sc = g[f] * rsqrtf(v + BN_EPS);
    float sh = b[f] - m * sc;
    out[t] = fmaf(hin[t], sc, sh);
}

// ---------------- launch ----------------

static inline char* bump(char*& p, size_t bytes) {
    char* r = p;
    p += (bytes + 255) & ~(size_t)255;
    return r;
}

extern "C" void kernel_launch(void* const* d_in, const int* in_sizes, int n_in,
                              void* d_out, int out_size, void* d_ws, size_t ws_size,
                              hipStream_t stream) {
    const float* x   = (const float*)d_in[0];
    const int* eic   = (const int*)d_in[1];
    const int* eid   = (const int*)d_in[2];
    const float* W1l = (const float*)d_in[3];
    const float* W1r = (const float*)d_in[4];
    const float* W2l = (const float*)d_in[5];
    const float* W2r = (const float*)d_in[6];
    const float* W3l = (const float*)d_in[7];
    const float* W3r = (const float*)d_in[8];
    const float* W4l = (const float*)d_in[9];
    const float* W4r = (const float*)d_in[10];
    const float* g1 = (const float*)d_in[11];
    const float* b1 = (const float*)d_in[12];
    const float* g2 = (const float*)d_in[13];
    const float* b2 = (const float*)d_in[14];
    const float* g3 = (const float*)d_in[15];
    const float* b3 = (const float*)d_in[16];
    const float* g4 = (const float*)d_in[17];
    const float* b4 = (const float*)d_in[18];
    float* out = (float*)d_out;

    char* p = (char*)d_ws;
    float* stats   = (float*)bump(p, 5 * 256 * 4);   // zero region (only this)
    size_t zero_bytes = (size_t)(p - (char*)d_ws);
    int*   bhist_c = (int*)  bump(p, (size_t)NSB * NCH * 4);
    int*   bhist_d = (int*)  bump(p, (size_t)NSB * NCH * 4);
    int*   total_c = (int*)  bump(p, NSB * 4);
    int*   bbase_c = (int*)  bump(p, NSB * 4);
    int*   total_d = (int*)  bump(p, NSB * 4);
    int*   bbase_d = (int*)  bump(p, NSB * 4);
    int*   offs_c  = (int*)  bump(p, NN * 4);
    int*   deg_c   = (int*)  bump(p, NN * 4);
    float* inv_c   = (float*)bump(p, NN * 4);
    int*   offs_d  = (int*)  bump(p, NN * 4);
    int*   deg_d   = (int*)  bump(p, NN * 4);
    float* inv_d   = (float*)bump(p, NN * 4);
    int*   csr_c   = (int*)  bump(p, (size_t)EC * 4);
    int*   csr_d   = (int*)  bump(p, (size_t)ED * 4);
    unsigned* packed_d = (unsigned*)bump(p, (size_t)ED * 4);
    // packed_c dead after sb_csr; overlay activation ping-pong buffers on it
    char* pc = p;
    unsigned* packed_c = (unsigned*)bump(p, (size_t)EC * 4);
    char* pr = pc;
    float* r_a = (float*)bump(pr, NN * 8 * 4);
    float* r_b = (float*)bump(pr, NN * 8 * 4);
    (void)ws_size; (void)in_sizes; (void)n_in; (void)out_size;

    hipMemsetAsync(d_ws, 0, zero_bytes, stream);

    hist_pass<<<NCH, 1024, 0, stream>>>(eic, EC, bhist_c);
    hist_pass<<<NCH, 1024, 0, stream>>>(eid, ED, bhist_d);
    row_scan<<<NSB, 256, 0, stream>>>(bhist_c, total_c);
    row_scan<<<NSB, 256, 0, stream>>>(bhist_d, total_d);
    bucket_base<<<1, 256, 0, stream>>>(total_c, bbase_c);
    bucket_base<<<1, 256, 0, stream>>>(total_d, bbase_d);
    scatter_pairs<<<NCH, 1024, 0, stream>>>(eic, EC, bhist_c, bbase_c, packed_c);
    scatter_pairs<<<NCH, 1024, 0, stream>>>(eid, ED, bhist_d, bbase_d, packed_d);
    sb_csr<<<NSB, 256, 0, stream>>>(packed_c, bbase_c, total_c, csr_c, offs_c, deg_c, inv_c);
    sb_csr<<<NSB, 256, 0, stream>>>(packed_d, bbase_d, total_d, csr_d, offs_d, deg_d, inv_d);

    const int LB = 2048;   // 8192 waves; grid-stride over nodes
    sage_layer<5, false><<<LB, 256, 0, stream>>>(
        x, nullptr, nullptr, nullptr,
        offs_c, deg_c, csr_c, inv_c, W1l, W1r, r_a, stats + 0);
    sage_layer<8, true><<<LB, 256, 0, stream>>>(
        r_a, stats + 0, g1, b1,
        offs_c, deg_c, csr_c, inv_c, W4l, W4r, r_b, stats + 256);
    sage_layer<8, true><<<LB, 256, 0, stream>>>(
        r_b, stats + 256, g2, b2,
        offs_d, deg_d, csr_d, inv_d, W2l, W2r, r_a, stats + 512);
    sage_layer<8, true><<<LB, 256, 0, stream>>>(
        r_a, stats + 512, g3, b3,
        offs_c, deg_c, csr_c, inv_c, W3l, W3r, r_b, stats + 768);
    sage_layer<8, true><<<LB, 256, 0, stream>>>(
        r_b, stats + 768, g4, b4,
        offs_c, deg_c, csr_c, inv_c, W3l, W3r, r_a, stats + 1024);
    apply_bn_out<<<(NN * 8 + 255) / 256, 256, 0, stream>>>(r_a, stats + 1024, g4, b4, out);
}

// Round 8
// 639.944 us; speedup vs baseline: 1.4048x; 1.1411x over previous
//
#include <hip/hip_runtime.h>

#define NN 100000
#define EC 6400000
#define ED 400000
#define BN_EPS 1e-5f
#define NSB ((NN + 255) >> 8)    // 391 buckets of 256 nodes
#define NCH 256                  // edge chunks == scatter/hist grid
#define CSR_CAP 19200            // LDS CSR build capacity (mean 16384 + 22 sigma)
#define CHUNK_OF(E) (((((E) + NCH - 1) / NCH) + 3) & ~3)   // 4-aligned chunk

// ---------------- preprocessing (unchanged from R5-R7, proven) ----------------

__global__ __launch_bounds__(1024)
void hist_pass(const int* __restrict__ ei, int E, int* __restrict__ bhist) {
    __shared__ int h[NSB];
    for (int i = threadIdx.x; i < NSB; i += 1024) h[i] = 0;
    __syncthreads();
    int k = blockIdx.x;
    int chunk = CHUNK_OF(E);
    int beg = k * chunk, end = min(E, beg + chunk);
    for (int e = beg + threadIdx.x * 4; e < end; e += 1024 * 4) {
        int4 d4 = *(const int4*)&ei[E + e];
        atomicAdd(&h[d4.x >> 8], 1);
        atomicAdd(&h[d4.y >> 8], 1);
        atomicAdd(&h[d4.z >> 8], 1);
        atomicAdd(&h[d4.w >> 8], 1);
    }
    __syncthreads();
    for (int i = threadIdx.x; i < NSB; i += 1024) bhist[i * NCH + k] = h[i];
}

__global__ __launch_bounds__(256)
void row_scan(int* __restrict__ bhist, int* __restrict__ total) {
    int b = blockIdx.x;
    int* row = bhist + b * NCH;
    __shared__ int wsum[4];
    int lane = threadIdx.x & 63, w = threadIdx.x >> 6;
    int v = row[threadIdx.x];
    int x = v;
    #pragma unroll
    for (int sh = 1; sh < 64; sh <<= 1) { int y = __shfl_up(x, sh); if (lane >= sh) x += y; }
    if (lane == 63) wsum[w] = x;
    __syncthreads();
    int wb = 0;
    #pragma unroll
    for (int j = 0; j < 4; ++j) if (j < w) wb += wsum[j];
    row[threadIdx.x] = wb + x - v;
    if (threadIdx.x == 255) total[b] = wb + x;
}

__global__ void bucket_base(const int* __restrict__ total, int* __restrict__ bbase) {
    __shared__ int wsum[4];
    __shared__ int carry;
    if (threadIdx.x == 0) carry = 0;
    __syncthreads();
    int lane = threadIdx.x & 63, w = threadIdx.x >> 6;
    for (int s = 0; s < NSB; s += 256) {
        int idx = s + threadIdx.x;
        int v = (idx < NSB) ? total[idx] : 0;
        int x = v;
        #pragma unroll
        for (int sh = 1; sh < 64; sh <<= 1) { int y = __shfl_up(x, sh); if (lane >= sh) x += y; }
        if (lane == 63) wsum[w] = x;
        __syncthreads();
        int wb = 0;
        #pragma unroll
        for (int j = 0; j < 4; ++j) if (j < w) wb += wsum[j];
        int all = wsum[0] + wsum[1] + wsum[2] + wsum[3];
        if (idx < NSB) bbase[idx] = carry + wb + x - v;
        __syncthreads();
        if (threadIdx.x == 0) carry += all;
        __syncthreads();
    }
}

__global__ __launch_bounds__(1024)
void scatter_pairs(const int* __restrict__ ei, int E,
                   const int* __restrict__ bhist, const int* __restrict__ bbase,
                   unsigned* __restrict__ packed) {
    __shared__ int cur[NSB];
    int k = blockIdx.x;
    for (int b = threadIdx.x; b < NSB; b += 1024)
        cur[b] = bbase[b] + bhist[b * NCH + k];
    __syncthreads();
    int chunk = CHUNK_OF(E);
    int beg = k * chunk, end = min(E, beg + chunk);
    for (int e = beg + threadIdx.x * 4; e < end; e += 1024 * 4) {
        int4 s4 = *(const int4*)&ei[e];
        int4 d4 = *(const int4*)&ei[E + e];
        { int p = atomicAdd(&cur[d4.x >> 8], 1); packed[p] = (unsigned)s4.x | ((unsigned)(d4.x & 255) << 17); }
        { int p = atomicAdd(&cur[d4.y >> 8], 1); packed[p] = (unsigned)s4.y | ((unsigned)(d4.y & 255) << 17); }
        { int p = atomicAdd(&cur[d4.z >> 8], 1); packed[p] = (unsigned)s4.z | ((unsigned)(d4.z & 255) << 17); }
        { int p = atomicAdd(&cur[d4.w >> 8], 1); packed[p] = (unsigned)s4.w | ((unsigned)(d4.w & 255) << 17); }
    }
}

__global__ __launch_bounds__(256)
void sb_csr(const unsigned* __restrict__ packed,
            const int* __restrict__ bbase, const int* __restrict__ total,
            int* __restrict__ csr, int* __restrict__ offs, int* __restrict__ deg,
            float* __restrict__ inv) {
    __shared__ int h[256];
    __shared__ int loff[256];
    __shared__ int ws2[4];
    __shared__ int ebuf[CSR_CAP];
    int b = blockIdx.x;
    int ebeg = bbase[b], ecnt = total[b];
    int node0 = b << 8;
    int nn = min(256, NN - node0);
    h[threadIdx.x] = 0;
    __syncthreads();
    for (int e = threadIdx.x; e < ecnt; e += 256)
        atomicAdd(&h[packed[ebeg + e] >> 17], 1);
    __syncthreads();
    {
        int lane = threadIdx.x & 63, w = threadIdx.x >> 6;
        int v = h[threadIdx.x], x = v;
        #pragma unroll
        for (int sh = 1; sh < 64; sh <<= 1) { int y = __shfl_up(x, sh); if (lane >= sh) x += y; }
        if (lane == 63) ws2[w] = x;
        __syncthreads();
        int wb = 0;
        #pragma unroll
        for (int j = 0; j < 4; ++j) if (j < w) wb += ws2[j];
        int excl = wb + x - v;
        loff[threadIdx.x] = excl;
        if (threadIdx.x < nn) {
            int node = node0 + threadIdx.x;
            offs[node] = ebeg + excl;
            deg[node]  = v;
            inv[node]  = 1.0f / (float)(v > 1 ? v : 1);
        }
    }
    __syncthreads();
    if (ecnt <= CSR_CAP) {
        for (int e = threadIdx.x; e < ecnt; e += 256) {
            unsigned u = packed[ebeg + e];
            int p = atomicAdd(&loff[u >> 17], 1);
            ebuf[p] = (int)(u & 0x1FFFF);
        }
        __syncthreads();
        for (int e = threadIdx.x; e < ecnt; e += 256) csr[ebeg + e] = ebuf[e];
    } else {
        for (int e = threadIdx.x; e < ecnt; e += 256) {
            unsigned u = packed[ebeg + e];
            int p = atomicAdd(&loff[u >> 17], 1);
            csr[ebeg + p] = (int)(u & 0x1FFFF);
        }
    }
}

// prep: x (f32 [NN,5]) -> f32 padded [NN,8]; W1 (8x5) -> padded 8x8
__global__ __launch_bounds__(256)
void prep_misc(const float* __restrict__ x, const float* __restrict__ W1l,
               const float* __restrict__ W1r, float* __restrict__ xp,
               float* __restrict__ W1lp, float* __restrict__ W1rp) {
    int t = blockIdx.x * 256 + threadIdx.x;
    if (t < 64) {
        int f = t >> 3, k = t & 7;
        W1lp[t] = (k < 5) ? W1l[f * 5 + k] : 0.f;
        W1rp[t] = (k < 5) ? W1r[f * 5 + k] : 0.f;
    }
    for (int idx = t; idx < NN * 8; idx += gridDim.x * 256) {
        int f = idx & 7, i = idx >> 3;
        xp[idx] = (f < 5) ? x[i * 5 + f] : 0.f;
    }
}

// ---------------- fused SAGE layer v3 ----------------
// f32 rows (32B): R7's bf16 storage amplified quantization ~30x through
// L2-normalize (small ||out|| tail) + BN (1/sigma) over 4 layers ->
// absmax 0.52. f32 storage (R5-proven, absmax 0.0156) + R6/R7 structure:
// one lane per edge, two independent dwordx4 row loads, 3 shfl_xor rounds
// -> all 8 lanes hold all 8 sums -> shuffle-free matmul; deg=0 BN-shift fix.
template<bool APPLY_BN>
__global__ __launch_bounds__(256)
void sage_layer8(const float* __restrict__ hin,
                 const float* __restrict__ stats_in,   // padded: [k*16]=sum, [(8+k)*16]=sumsq
                 const float* __restrict__ gin, const float* __restrict__ bin,
                 const int* __restrict__ offs, const int* __restrict__ deg,
                 const int* __restrict__ csr, const float* __restrict__ inv,
                 const float* __restrict__ Wl, const float* __restrict__ Wr,
                 float* __restrict__ hout, float* __restrict__ stats_out) {
    __shared__ float bl[16];
    int tid = threadIdx.x;
    if (tid < 16) bl[tid] = 0.f;
    __syncthreads();
    int wave = tid >> 6, lane = tid & 63, g = lane >> 3, f = lane & 7;

    float sc[8], sh[8];
    #pragma unroll
    for (int k = 0; k < 8; ++k) { sc[k] = 1.f; sh[k] = 0.f; }
    if constexpr (APPLY_BN) {
        #pragma unroll
        for (int k = 0; k < 8; ++k) {
            float m = stats_in[k * 16] * (1.f / NN);
            float v = stats_in[(8 + k) * 16] * (1.f / NN) - m * m;
            float is = rsqrtf(v + BN_EPS);
            sc[k] = gin[k] * is;
            sh[k] = bin[k] - m * sc[k];
        }
    }
    float wl[8], wr[8];
    #pragma unroll
    for (int k = 0; k < 8; ++k) { wl[k] = Wl[f * 8 + k]; wr[k] = Wr[f * 8 + k]; }

    float acc_r = 0.f, acc_r2 = 0.f;
    const int stride = gridDim.x * 32;            // blocks * 4 waves * 8 nodes
    for (int i0 = (blockIdx.x * 4 + wave) * 8; i0 < NN; i0 += stride) {
        int i = i0 + g;
        int ic = min(i, NN - 1);
        bool ok = (i < NN);
        int d = ok ? deg[ic] : 0;
        int o = offs[ic];
        float a0 = 0, a1 = 0, a2 = 0, a3 = 0, a4 = 0, a5 = 0, a6 = 0, a7 = 0;
        for (int b = 0; b < d; b += 8) {          // divergent per group: exec-masked
            int e = b + f;
            int cv = csr[o + e];                  // <=7 over-read: csr tail-padded
            float m = (e < d) ? 1.f : 0.f;
            unsigned s = min((unsigned)cv & 0x1FFFFu, (unsigned)(NN - 1));
            const float4* rp = (const float4*)(hin + (size_t)s * 8);
            float4 r0 = rp[0];                    // two independent 16B loads
            float4 r1 = rp[1];
            a0 = fmaf(r0.x, m, a0); a1 = fmaf(r0.y, m, a1);
            a2 = fmaf(r0.z, m, a2); a3 = fmaf(r0.w, m, a3);
            a4 = fmaf(r1.x, m, a4); a5 = fmaf(r1.y, m, a5);
            a6 = fmaf(r1.z, m, a6); a7 = fmaf(r1.w, m, a7);
        }
        #pragma unroll
        for (int msk = 1; msk < 8; msk <<= 1) {   // group-wide sums, all lanes
            a0 += __shfl_xor(a0, msk); a1 += __shfl_xor(a1, msk);
            a2 += __shfl_xor(a2, msk); a3 += __shfl_xor(a3, msk);
            a4 += __shfl_xor(a4, msk); a5 += __shfl_xor(a5, msk);
            a6 += __shfl_xor(a6, msk); a7 += __shfl_xor(a7, msk);
        }
        float im = inv[ic];
        float dnz = (d > 0) ? 1.f : 0.f;          // BN shift only if node has neighbors
        const float4* hp = (const float4*)(hin + (size_t)ic * 8);
        float4 h0 = hp[0];
        float4 h1 = hp[1];
        float hk[8] = { h0.x, h0.y, h0.z, h0.w, h1.x, h1.y, h1.z, h1.w };
        float ac[8] = { a0, a1, a2, a3, a4, a5, a6, a7 };
        float y = 0.f;
        #pragma unroll
        for (int k = 0; k < 8; ++k) {
            float mk = fmaf(sc[k], ac[k] * im, sh[k] * dnz);
            float hh = fmaf(sc[k], hk[k], sh[k]);
            y = fmaf(mk, wl[k], y);
            y = fmaf(hh, wr[k], y);
        }
        float n2 = y * y;
        n2 += __shfl_xor(n2, 1);
        n2 += __shfl_xor(n2, 2);
        n2 += __shfl_xor(n2, 4);
        float z = y / fmaxf(sqrtf(n2), 1e-12f);
        float r = fmaxf(z, 0.f);
        r = ok ? r : 0.f;
        if (ok) hout[(size_t)i * 8 + f] = r;      // 64 consecutive floats: coalesced
        acc_r += r;
        acc_r2 += r * r;
    }
    atomicAdd(&bl[f], acc_r);
    atomicAdd(&bl[8 + f], acc_r2);
    __syncthreads();
    if (tid < 16) atomicAdd(&stats_out[tid * 16], bl[tid]);   // 1 cache line per feature
}

__global__ void apply_bn_out(const float* __restrict__ hin,
                             const float* __restrict__ stats,
                             const float* __restrict__ g, const float* __restrict__ b,
                             float* __restrict__ out) {
    int t = blockIdx.x * blockDim.x + threadIdx.x;
    if (t >= NN * 8) return;
    int f = t & 7;
    float m = stats[f * 16] * (1.0f / NN);
    float v = stats[(8 + f) * 16] * (1.0f / NN) - m * m;
    float sc = g[f] * rsqrtf(v + BN_EPS);
    float sh = b[f] - m * sc;
    out[t] = fmaf(hin[t], sc, sh);
}

// ---------------- launch ----------------

static inline char* bump(char*& p, size_t bytes) {
    char* r = p;
    p += (bytes + 255) & ~(size_t)255;
    return r;
}

extern "C" void kernel_launch(void* const* d_in, const int* in_sizes, int n_in,
                              void* d_out, int out_size, void* d_ws, size_t ws_size,
                              hipStream_t stream) {
    const float* x   = (const float*)d_in[0];
    const int* eic   = (const int*)d_in[1];
    const int* eid   = (const int*)d_in[2];
    const float* W1l = (const float*)d_in[3];
    const float* W1r = (const float*)d_in[4];
    const float* W2l = (const float*)d_in[5];
    const float* W2r = (const float*)d_in[6];
    const float* W3l = (const float*)d_in[7];
    const float* W3r = (const float*)d_in[8];
    const float* W4l = (const float*)d_in[9];
    const float* W4r = (const float*)d_in[10];
    const float* g1 = (const float*)d_in[11];
    const float* b1 = (const float*)d_in[12];
    const float* g2 = (const float*)d_in[13];
    const float* b2 = (const float*)d_in[14];
    const float* g3 = (const float*)d_in[15];
    const float* b3 = (const float*)d_in[16];
    const float* g4 = (const float*)d_in[17];
    const float* b4 = (const float*)d_in[18];
    float* out = (float*)d_out;

    char* p = (char*)d_ws;
    float* stats   = (float*)bump(p, 5 * 256 * 4);   // zero region (only this)
    size_t zero_bytes = (size_t)(p - (char*)d_ws);
    int*   bhist_c = (int*)  bump(p, (size_t)NSB * NCH * 4);
    int*   bhist_d = (int*)  bump(p, (size_t)NSB * NCH * 4);
    int*   total_c = (int*)  bump(p, NSB * 4);
    int*   bbase_c = (int*)  bump(p, NSB * 4);
    int*   total_d = (int*)  bump(p, NSB * 4);
    int*   bbase_d = (int*)  bump(p, NSB * 4);
    int*   offs_c  = (int*)  bump(p, NN * 4);
    int*   deg_c   = (int*)  bump(p, NN * 4);
    float* inv_c   = (float*)bump(p, NN * 4);
    int*   offs_d  = (int*)  bump(p, NN * 4);
    int*   deg_d   = (int*)  bump(p, NN * 4);
    float* inv_d   = (float*)bump(p, NN * 4);
    int*   csr_c   = (int*)  bump(p, ((size_t)EC + 64) * 4);   // +64 over-read pad
    int*   csr_d   = (int*)  bump(p, ((size_t)ED + 64) * 4);
    float* xp32    = (float*)bump(p, (size_t)NN * 8 * 4);
    float* W1lp    = (float*)bump(p, 64 * 4);
    float* W1rp    = (float*)bump(p, 64 * 4);
    unsigned* packed_d = (unsigned*)bump(p, (size_t)ED * 4);
    // packed_c dead after sb_csr; overlay f32 activation ping-pong buffers
    char* pc = p;
    unsigned* packed_c = (unsigned*)bump(p, (size_t)EC * 4);
    char* pr = pc;
    float* r_a = (float*)bump(pr, (size_t)NN * 8 * 4);
    float* r_b = (float*)bump(pr, (size_t)NN * 8 * 4);
    (void)ws_size; (void)in_sizes; (void)n_in; (void)out_size;

    hipMemsetAsync(d_ws, 0, zero_bytes, stream);

    hist_pass<<<NCH, 1024, 0, stream>>>(eic, EC, bhist_c);
    hist_pass<<<NCH, 1024, 0, stream>>>(eid, ED, bhist_d);
    row_scan<<<NSB, 256, 0, stream>>>(bhist_c, total_c);
    row_scan<<<NSB, 256, 0, stream>>>(bhist_d, total_d);
    bucket_base<<<1, 256, 0, stream>>>(total_c, bbase_c);
    bucket_base<<<1, 256, 0, stream>>>(total_d, bbase_d);
    scatter_pairs<<<NCH, 1024, 0, stream>>>(eic, EC, bhist_c, bbase_c, packed_c);
    scatter_pairs<<<NCH, 1024, 0, stream>>>(eid, ED, bhist_d, bbase_d, packed_d);
    sb_csr<<<NSB, 256, 0, stream>>>(packed_c, bbase_c, total_c, csr_c, offs_c, deg_c, inv_c);
    sb_csr<<<NSB, 256, 0, stream>>>(packed_d, bbase_d, total_d, csr_d, offs_d, deg_d, inv_d);
    prep_misc<<<512, 256, 0, stream>>>(x, W1l, W1r, xp32, W1lp, W1rp);

    const int LB = 2048;   // 8192 waves x 8 nodes/wave per grid-iteration
    sage_layer8<false><<<LB, 256, 0, stream>>>(
        xp32, nullptr, nullptr, nullptr,
        offs_c, deg_c, csr_c, inv_c, W1lp, W1rp, r_a, stats + 0);
    sage_layer8<true><<<LB, 256, 0, stream>>>(
        r_a, stats + 0, g1, b1,
        offs_c, deg_c, csr_c, inv_c, W4l, W4r, r_b, stats + 256);
    sage_layer8<true><<<LB, 256, 0, stream>>>(
        r_b, stats + 256, g2, b2,
        offs_d, deg_d, csr_d, inv_d, W2l, W2r, r_a, stats + 512);
    sage_layer8<true><<<LB, 256, 0, stream>>>(
        r_a, stats + 512, g3, b3,
        offs_c, deg_c, csr_c, inv_c, W3l, W3r, r_b, stats + 768);
    sage_layer8<true><<<LB, 256, 0, stream>>>(
        r_b, stats + 768, g4, b4,
        offs_c, deg_c, csr_c, inv_c, W3l, W3r, r_a, stats + 1024);
    apply_bn_out<<<(NN * 8 + 255) / 256, 256, 0, stream>>>(r_a, stats + 1024, g4, b4, out);
}